// Round 4
// baseline (157.967 us; speedup 1.0000x reference)
//
#include <hip/hip_runtime.h>
#include <cstddef>

#define NN 4096
#define UF 128
#define NE 131072

// ---------- edge dtype handling (int64 vs int32 storage) ----------
__device__ __forceinline__ int edge_at(const void* ei, int is64, int idx) {
  if (is64) return (int)((const long long*)ei)[idx];
  return ((const int*)ei)[idx];
}

__global__ void k_init(int* __restrict__ flag, int* __restrict__ deg) {
  int t = blockIdx.x * blockDim.x + threadIdx.x;
  if (t == 0) flag[0] = 1;  // assume int64 until disproven
  if (t < NN) deg[t] = 0;
}

// Wave-ballot + plain store (benign race); NO per-thread atomics.
__global__ void k_detect(const long long* __restrict__ ei64, int* __restrict__ flag) {
  int t = blockIdx.x * blockDim.x + threadIdx.x;
  long long v = ei64[t];
  bool viol = (v < 0 || v >= NN);
  if (__ballot(viol)) {
    if ((threadIdx.x & 63) == 0) flag[0] = 0;
  }
}

// ---------- CSR build ----------
__global__ void k_count(const void* __restrict__ ei, const int* __restrict__ flag,
                        int* __restrict__ deg) {
  int e = blockIdx.x * blockDim.x + threadIdx.x;
  if (e >= NE) return;
  int is64 = flag[0];
  int d = edge_at(ei, is64, NE + e);
  atomicAdd(&deg[d], 1);
}

// shfl-based scan: 2 barriers (was 20)
__global__ __launch_bounds__(1024) void k_scan(const int* __restrict__ deg,
                                               int* __restrict__ rowstart,
                                               int* __restrict__ cursor) {
  __shared__ int wsum[16];
  __shared__ int woff[17];
  const int t = threadIdx.x;
  const int lane = t & 63, w = t >> 6;
  int4 v = *(const int4*)(deg + t * 4);
  int s = v.x + v.y + v.z + v.w;
  int inc = s;
#pragma unroll
  for (int d = 1; d < 64; d <<= 1) {
    int u = __shfl_up(inc, d, 64);
    if (lane >= d) inc += u;
  }
  if (lane == 63) wsum[w] = inc;
  __syncthreads();
  if (t == 0) {
    int acc = 0;
#pragma unroll
    for (int i = 0; i < 16; ++i) { woff[i] = acc; acc += wsum[i]; }
    woff[16] = acc;
    rowstart[NN] = acc;
  }
  __syncthreads();
  int excl = woff[w] + inc - s;   // exclusive prefix for this thread's 4 nodes
  int r0 = excl, r1 = r0 + v.x, r2 = r1 + v.y, r3 = r2 + v.z;
  int4 rs; rs.x = r0; rs.y = r1; rs.z = r2; rs.w = r3;
  *(int4*)(rowstart + t * 4) = rs;
  *(int4*)(cursor + t * 4) = rs;
}

__global__ void k_scatter(const void* __restrict__ ei, const int* __restrict__ flag,
                          int* __restrict__ cursor, int* __restrict__ csr) {
  int e = blockIdx.x * blockDim.x + threadIdx.x;
  if (e >= NE) return;
  int is64 = flag[0];
  int s = edge_at(ei, is64, e);
  int d = edge_at(ei, is64, NE + e);
  int pos = atomicAdd(&cursor[d], 1);
  csr[pos] = s;
}

// ---------- fused aggregate + SAGE layer ----------
// Block = 16 nodes, 256 threads. Phase A: 4 waves gather the 16 nodes' mean
// neighborhoods straight into As[.][0:128) (no global agg buffer). Phase B:
// own rows -> As[.][128:256). Phase C: K=256 GEMM vs W'=[Wl|Wr] staged in
// KC=32 chunks (transposed in LDS; hot loop pure ds_read+fma).
template<bool TANH>
__global__ __launch_bounds__(256) void k_fused_layer(
    const float* __restrict__ feat, const int* __restrict__ rowstart,
    const int* __restrict__ csr,
    const float* __restrict__ Wl, const float* __restrict__ bl,
    const float* __restrict__ Wr, float* __restrict__ out) {
  __shared__ float As[16][260];    // 16 nodes x K=256 (+pad)
  __shared__ float Ws[32][132];    // K-chunk x 128 outs (+pad)
  const int t = threadIdx.x;
  const int base = blockIdx.x * 16;
  const int wave = t >> 6, lane = t & 63;

  // Phase A: aggregate; wave handles nodes wave*4 .. wave*4+3
#pragma unroll
  for (int r = 0; r < 4; ++r) {
    int node = base + wave * 4 + r;
    int s0 = rowstart[node], s1 = rowstart[node + 1];
    float f0 = 0.f, f1 = 0.f;
#pragma unroll 4
    for (int e = s0; e < s1; ++e) {
      int s = csr[e];
      float2 v = *((const float2*)(feat + (size_t)s * UF) + lane);
      f0 += v.x; f1 += v.y;
    }
    float inv = 1.0f / (float)max(s1 - s0, 1);
    As[wave * 4 + r][lane * 2]     = f0 * inv;
    As[wave * 4 + r][lane * 2 + 1] = f1 * inv;
  }
  // Phase B: own rows (512 float4 / 256 threads = 2 each)
#pragma unroll
  for (int rr = 0; rr < 2; ++rr) {
    int idx = t + 256 * rr;
    int row = idx >> 5;
    int c = (idx & 31) * 4;
    *(float4*)&As[row][128 + c] = *(const float4*)(feat + (size_t)(base + row) * UF + c);
  }

  const int o0 = (t & 31) * 4;
  const int n0 = (t >> 5) * 2;
  const int wo = t & 127;          // W-stage: output row handled by this thread
  const int kqb = (t >> 7) * 4;    // W-stage: which 4 of the 8 float4-groups
  float acc[2][4] = {};

  for (int kc = 0; kc < 8; ++kc) {
    __syncthreads();               // covers Phase A/B on first iter, Ws reuse after
#pragma unroll
    for (int q = 0; q < 4; ++q) {
      int kq = kqb + q;                       // 0..7
      int kg = kc * 32 + kq * 4;              // global k of this float4
      const float* src = (kg < 128) ? (Wl + (size_t)wo * UF + kg)
                                    : (Wr + (size_t)wo * UF + (kg - 128));
      float4 w = *(const float4*)src;
      Ws[kq * 4 + 0][wo] = w.x;
      Ws[kq * 4 + 1][wo] = w.y;
      Ws[kq * 4 + 2][wo] = w.z;
      Ws[kq * 4 + 3][wo] = w.w;
    }
    __syncthreads();
#pragma unroll 4
    for (int kw = 0; kw < 8; ++kw) {
      int k = kc * 32 + kw * 4;
      float4 a0 = *(const float4*)&As[n0][k];
      float4 a1 = *(const float4*)&As[n0 + 1][k];
      float4 w0 = *(const float4*)&Ws[kw * 4 + 0][o0];
      float4 w1 = *(const float4*)&Ws[kw * 4 + 1][o0];
      float4 w2 = *(const float4*)&Ws[kw * 4 + 2][o0];
      float4 w3 = *(const float4*)&Ws[kw * 4 + 3][o0];
      acc[0][0] = fmaf(a0.x, w0.x, acc[0][0]); acc[0][1] = fmaf(a0.x, w0.y, acc[0][1]);
      acc[0][2] = fmaf(a0.x, w0.z, acc[0][2]); acc[0][3] = fmaf(a0.x, w0.w, acc[0][3]);
      acc[1][0] = fmaf(a1.x, w0.x, acc[1][0]); acc[1][1] = fmaf(a1.x, w0.y, acc[1][1]);
      acc[1][2] = fmaf(a1.x, w0.z, acc[1][2]); acc[1][3] = fmaf(a1.x, w0.w, acc[1][3]);
      acc[0][0] = fmaf(a0.y, w1.x, acc[0][0]); acc[0][1] = fmaf(a0.y, w1.y, acc[0][1]);
      acc[0][2] = fmaf(a0.y, w1.z, acc[0][2]); acc[0][3] = fmaf(a0.y, w1.w, acc[0][3]);
      acc[1][0] = fmaf(a1.y, w1.x, acc[1][0]); acc[1][1] = fmaf(a1.y, w1.y, acc[1][1]);
      acc[1][2] = fmaf(a1.y, w1.z, acc[1][2]); acc[1][3] = fmaf(a1.y, w1.w, acc[1][3]);
      acc[0][0] = fmaf(a0.z, w2.x, acc[0][0]); acc[0][1] = fmaf(a0.z, w2.y, acc[0][1]);
      acc[0][2] = fmaf(a0.z, w2.z, acc[0][2]); acc[0][3] = fmaf(a0.z, w2.w, acc[0][3]);
      acc[1][0] = fmaf(a1.z, w2.x, acc[1][0]); acc[1][1] = fmaf(a1.z, w2.y, acc[1][1]);
      acc[1][2] = fmaf(a1.z, w2.z, acc[1][2]); acc[1][3] = fmaf(a1.z, w2.w, acc[1][3]);
      acc[0][0] = fmaf(a0.w, w3.x, acc[0][0]); acc[0][1] = fmaf(a0.w, w3.y, acc[0][1]);
      acc[0][2] = fmaf(a0.w, w3.z, acc[0][2]); acc[0][3] = fmaf(a0.w, w3.w, acc[0][3]);
      acc[1][0] = fmaf(a1.w, w3.x, acc[1][0]); acc[1][1] = fmaf(a1.w, w3.y, acc[1][1]);
      acc[1][2] = fmaf(a1.w, w3.z, acc[1][2]); acc[1][3] = fmaf(a1.w, w3.w, acc[1][3]);
    }
  }
#pragma unroll
  for (int i = 0; i < 2; ++i) {
    float4 r;
    r.x = acc[i][0] + bl[o0 + 0];
    r.y = acc[i][1] + bl[o0 + 1];
    r.z = acc[i][2] + bl[o0 + 2];
    r.w = acc[i][3] + bl[o0 + 3];
    if (TANH) { r.x = tanhf(r.x); r.y = tanhf(r.y); r.z = tanhf(r.z); r.w = tanhf(r.w); }
    *(float4*)(out + (size_t)(base + n0 + i) * UF + o0) = r;
  }
}

// ---------- fused aggregate + actor/critic heads (KC=16, two W pairs) ----------
__global__ __launch_bounds__(256) void k_fused_heads(
    const float* __restrict__ feat, const int* __restrict__ rowstart,
    const int* __restrict__ csr,
    const float* __restrict__ Wa_l, const float* __restrict__ ba_l,
    const float* __restrict__ Wa_r,
    const float* __restrict__ Wcr_l, const float* __restrict__ bcr_l,
    const float* __restrict__ Wcr_r,
    const float* __restrict__ Wfa, const float* __restrict__ Wfc,
    float* __restrict__ a1, float* __restrict__ a2, float* __restrict__ cp) {
  __shared__ float As[16][260];
  __shared__ float WsA[16][132];
  __shared__ float WsC[16][132];
  __shared__ float red[3][16][33];
  const int t = threadIdx.x;
  const int base = blockIdx.x * 16;
  const int wave = t >> 6, lane = t & 63;

#pragma unroll
  for (int r = 0; r < 4; ++r) {
    int node = base + wave * 4 + r;
    int s0 = rowstart[node], s1 = rowstart[node + 1];
    float f0 = 0.f, f1 = 0.f;
#pragma unroll 4
    for (int e = s0; e < s1; ++e) {
      int s = csr[e];
      float2 v = *((const float2*)(feat + (size_t)s * UF) + lane);
      f0 += v.x; f1 += v.y;
    }
    float inv = 1.0f / (float)max(s1 - s0, 1);
    As[wave * 4 + r][lane * 2]     = f0 * inv;
    As[wave * 4 + r][lane * 2 + 1] = f1 * inv;
  }
#pragma unroll
  for (int rr = 0; rr < 2; ++rr) {
    int idx = t + 256 * rr;
    int row = idx >> 5;
    int c = (idx & 31) * 4;
    *(float4*)&As[row][128 + c] = *(const float4*)(feat + (size_t)(base + row) * UF + c);
  }

  const int og = t & 31;
  const int o0 = og * 4;
  const int n0 = (t >> 5) * 2;
  const int wo = t & 127;
  const int kqb = (t >> 7) * 2;    // which 2 of the 4 float4-groups (KC=16)
  float accA[2][4] = {};
  float accC[2][4] = {};

  for (int kc = 0; kc < 16; ++kc) {
    __syncthreads();
#pragma unroll
    for (int q = 0; q < 2; ++q) {
      int kq = kqb + q;                       // 0..3
      int kg = kc * 16 + kq * 4;
      const float* sA = (kg < 128) ? (Wa_l  + (size_t)wo * UF + kg)
                                   : (Wa_r  + (size_t)wo * UF + (kg - 128));
      const float* sC = (kg < 128) ? (Wcr_l + (size_t)wo * UF + kg)
                                   : (Wcr_r + (size_t)wo * UF + (kg - 128));
      float4 wa = *(const float4*)sA;
      float4 wc = *(const float4*)sC;
      WsA[kq*4+0][wo] = wa.x; WsA[kq*4+1][wo] = wa.y;
      WsA[kq*4+2][wo] = wa.z; WsA[kq*4+3][wo] = wa.w;
      WsC[kq*4+0][wo] = wc.x; WsC[kq*4+1][wo] = wc.y;
      WsC[kq*4+2][wo] = wc.z; WsC[kq*4+3][wo] = wc.w;
    }
    __syncthreads();
#pragma unroll 2
    for (int kw = 0; kw < 4; ++kw) {
      int k = kc * 16 + kw * 4;
      float4 a0 = *(const float4*)&As[n0][k];
      float4 a1v = *(const float4*)&As[n0 + 1][k];
#pragma unroll
      for (int j = 0; j < 4; ++j) {
        float4 wa = *(const float4*)&WsA[kw * 4 + j][o0];
        float4 wc = *(const float4*)&WsC[kw * 4 + j][o0];
        float e0 = (j == 0) ? a0.x : (j == 1) ? a0.y : (j == 2) ? a0.z : a0.w;
        float e1 = (j == 0) ? a1v.x : (j == 1) ? a1v.y : (j == 2) ? a1v.z : a1v.w;
        accA[0][0] = fmaf(e0, wa.x, accA[0][0]); accA[0][1] = fmaf(e0, wa.y, accA[0][1]);
        accA[0][2] = fmaf(e0, wa.z, accA[0][2]); accA[0][3] = fmaf(e0, wa.w, accA[0][3]);
        accA[1][0] = fmaf(e1, wa.x, accA[1][0]); accA[1][1] = fmaf(e1, wa.y, accA[1][1]);
        accA[1][2] = fmaf(e1, wa.z, accA[1][2]); accA[1][3] = fmaf(e1, wa.w, accA[1][3]);
        accC[0][0] = fmaf(e0, wc.x, accC[0][0]); accC[0][1] = fmaf(e0, wc.y, accC[0][1]);
        accC[0][2] = fmaf(e0, wc.z, accC[0][2]); accC[0][3] = fmaf(e0, wc.w, accC[0][3]);
        accC[1][0] = fmaf(e1, wc.x, accC[1][0]); accC[1][1] = fmaf(e1, wc.y, accC[1][1]);
        accC[1][2] = fmaf(e1, wc.z, accC[1][2]); accC[1][3] = fmaf(e1, wc.w, accC[1][3]);
      }
    }
  }
  // biases + project to a1/a2/cp partials
#pragma unroll
  for (int i = 0; i < 2; ++i) {
    float pa1 = 0.f, pa2 = 0.f, pc = 0.f;
#pragma unroll
    for (int j = 0; j < 4; ++j) {
      float xa = accA[i][j] + ba_l[o0 + j];
      float xc = accC[i][j] + bcr_l[o0 + j];
      pa1 = fmaf(xa, Wfa[o0 + j], pa1);
      pa2 = fmaf(xa, Wfa[UF + o0 + j], pa2);
      pc  = fmaf(xc, Wfc[o0 + j], pc);
    }
    red[0][n0 + i][og] = pa1;
    red[1][n0 + i][og] = pa2;
    red[2][n0 + i][og] = pc;
  }
  __syncthreads();
  if (t < 48) {
    int q = t >> 4, n = t & 15;
    float s = 0.f;
#pragma unroll
    for (int j = 0; j < 32; ++j) s += red[q][n][j];
    float* dst = (q == 0) ? a1 : (q == 1) ? a2 : cp;
    dst[base + n] = s;
  }
}

// ---------- global reductions: LSE constant + critic scalar (shfl, 2 barriers) ----------
__global__ __launch_bounds__(1024) void k_reduce(
    const float* __restrict__ a1, const float* __restrict__ a2,
    const float* __restrict__ cp, const float* __restrict__ bfc,
    float* __restrict__ consts, float* __restrict__ outc) {
  __shared__ float r0[16], r1[16], r2[16], r3[16], r4[16];
  const int t = threadIdx.x, lane = t & 63, w = t >> 6;
  float4 X = *(const float4*)(a1 + t * 4);
  float4 Y = *(const float4*)(a2 + t * 4);
  float4 C = *(const float4*)(cp + t * 4);
  float mx = fmaxf(fmaxf(X.x, X.y), fmaxf(X.z, X.w));
  float my = fmaxf(fmaxf(Y.x, Y.y), fmaxf(Y.z, Y.w));
#pragma unroll
  for (int d = 1; d < 64; d <<= 1) {
    mx = fmaxf(mx, __shfl_xor(mx, d, 64));
    my = fmaxf(my, __shfl_xor(my, d, 64));
  }
  if (lane == 0) { r0[w] = mx; r1[w] = my; }
  __syncthreads();
  float m1 = r0[0], m2 = r1[0];
#pragma unroll
  for (int i = 1; i < 16; ++i) { m1 = fmaxf(m1, r0[i]); m2 = fmaxf(m2, r1[i]); }
  float e1 = expf(X.x - m1) + expf(X.y - m1) + expf(X.z - m1) + expf(X.w - m1);
  float e2 = expf(Y.x - m2) + expf(Y.y - m2) + expf(Y.z - m2) + expf(Y.w - m2);
  float sc = C.x + C.y + C.z + C.w;
#pragma unroll
  for (int d = 1; d < 64; d <<= 1) {
    e1 += __shfl_xor(e1, d, 64);
    e2 += __shfl_xor(e2, d, 64);
    sc += __shfl_xor(sc, d, 64);
  }
  if (lane == 0) { r2[w] = e1; r3[w] = e2; r4[w] = sc; }
  __syncthreads();
  if (t == 0) {
    float s1 = 0.f, s2 = 0.f, scs = 0.f;
#pragma unroll
    for (int i = 0; i < 16; ++i) { s1 += r2[i]; s2 += r3[i]; scs += r4[i]; }
    consts[0] = -(m1 + m2 + logf(s1) + logf(s2));
    outc[0] = tanhf(scs * (1.0f / (float)NN) + bfc[0]);
  }
}

// ---------- N^2 output write ----------
__global__ __launch_bounds__(256) void k_write(
    const float* __restrict__ a1, const float* __restrict__ a2,
    const float* __restrict__ consts, float* __restrict__ out) {
  int gid = blockIdx.x * 256 + threadIdx.x;        // one float4 per thread
  int row = gid >> 10;                             // 1024 float4 per row
  int c = (gid & 1023) * 4;
  float C = consts[0] + a1[row];
  float4 v = *(const float4*)(a2 + c);
  float4 r; r.x = v.x + C; r.y = v.y + C; r.z = v.z + C; r.w = v.w + C;
  *(float4*)(out + (size_t)gid * 4) = r;
}

extern "C" void kernel_launch(void* const* d_in, const int* in_sizes, int n_in,
                              void* d_out, int out_size, void* d_ws, size_t ws_size,
                              hipStream_t stream) {
  const float* x     = (const float*)d_in[0];
  const void*  ei    = d_in[1];
  const float* Wf_l  = (const float*)d_in[3];
  const float* bf_l  = (const float*)d_in[4];
  const float* Wf_r  = (const float*)d_in[5];
  const float* Wcm_l = (const float*)d_in[6];
  const float* bcm_l = (const float*)d_in[7];
  const float* Wcm_r = (const float*)d_in[8];
  const float* Wa_l  = (const float*)d_in[9];
  const float* ba_l  = (const float*)d_in[10];
  const float* Wa_r  = (const float*)d_in[11];
  const float* Wcr_l = (const float*)d_in[12];
  const float* bcr_l = (const float*)d_in[13];
  const float* Wcr_r = (const float*)d_in[14];
  const float* Wfa   = (const float*)d_in[15];
  const float* Wfc   = (const float*)d_in[17];
  const float* bfc   = (const float*)d_in[18];
  float* out = (float*)d_out;

  char* b = (char*)d_ws;
  size_t off = 0;
  int* flag = (int*)(b + off); off += 256;
  float* consts = (float*)(b + off); off += 256;
  int* deg = (int*)(b + off); off += (size_t)NN * 4;
  int* rowstart = (int*)(b + off); off += (size_t)(NN + 64) * 4;
  int* cursor = (int*)(b + off); off += (size_t)NN * 4;
  int* csr = (int*)(b + off); off += (size_t)NE * 4;
  float* a1 = (float*)(b + off); off += (size_t)NN * 4;
  float* a2 = (float*)(b + off); off += (size_t)NN * 4;
  float* cp = (float*)(b + off); off += (size_t)NN * 4;
  float* h1 = (float*)(b + off); off += (size_t)NN * UF * 4;
  float* h2 = (float*)(b + off); off += (size_t)NN * UF * 4;
  if (ws_size < off) return;

  k_init<<<16, 256, 0, stream>>>(flag, deg);
  k_detect<<<NE / 256, 256, 0, stream>>>((const long long*)ei, flag);
  k_count<<<NE / 256, 256, 0, stream>>>(ei, flag, deg);
  k_scan<<<1, 1024, 0, stream>>>(deg, rowstart, cursor);
  k_scatter<<<NE / 256, 256, 0, stream>>>(ei, flag, cursor, csr);

  k_fused_layer<true><<<NN / 16, 256, 0, stream>>>(x, rowstart, csr, Wf_l, bf_l, Wf_r, h1);
  k_fused_layer<true><<<NN / 16, 256, 0, stream>>>(h1, rowstart, csr, Wcm_l, bcm_l, Wcm_r, h2);
  k_fused_heads<<<NN / 16, 256, 0, stream>>>(h2, rowstart, csr, Wa_l, ba_l, Wa_r,
                                             Wcr_l, bcr_l, Wcr_r, Wfa, Wfc, a1, a2, cp);
  k_reduce<<<1, 1024, 0, stream>>>(a1, a2, cp, bfc, consts, out + (size_t)NN * NN);
  k_write<<<(NN * NN) / 1024, 256, 0, stream>>>(a1, a2, consts, out);
}

// Round 5
// 140.112 us; speedup vs baseline: 1.1274x; 1.1274x over previous
//
#include <hip/hip_runtime.h>
#include <cstddef>

#define NN 4096
#define UF 128
#define NE 131072

// flag[0]: 0 = edges stored as int64 (default), 1 = stored as int32.
__device__ __forceinline__ int edge_at(const void* ei, int is32, int idx) {
  if (is32) return ((const int*)ei)[idx];
  return (int)((const long long*)ei)[idx];
}

// Read first NE elements as int64: if storage is int32 this covers the whole
// buffer and (s,d) pairs combine into huge values -> violation -> flag=1.
// If storage is int64 this covers the src row (all in [0,NN)) -> flag stays 0.
// Wave-ballot + plain store (benign race: all writers store 1).
__global__ void k_detect(const long long* __restrict__ ei64, int* __restrict__ flag) {
  int t = blockIdx.x * blockDim.x + threadIdx.x;
  long long v = ei64[t];
  bool viol = (v < 0 || v >= NN);
  if (__ballot(viol)) {
    if ((threadIdx.x & 63) == 0) flag[0] = 1;
  }
}

// ---------- CSR build ----------
__global__ void k_count(const void* __restrict__ ei, const int* __restrict__ flag,
                        int* __restrict__ deg) {
  int e = blockIdx.x * blockDim.x + threadIdx.x;
  if (e >= NE) return;
  int is32 = flag[0];
  int d = edge_at(ei, is32, NE + e);
  atomicAdd(&deg[d], 1);
}

// shfl-based scan: 2 barriers
__global__ __launch_bounds__(1024) void k_scan(const int* __restrict__ deg,
                                               int* __restrict__ rowstart,
                                               int* __restrict__ cursor) {
  __shared__ int wsum[16];
  __shared__ int woff[17];
  const int t = threadIdx.x;
  const int lane = t & 63, w = t >> 6;
  int4 v = *(const int4*)(deg + t * 4);
  int s = v.x + v.y + v.z + v.w;
  int inc = s;
#pragma unroll
  for (int d = 1; d < 64; d <<= 1) {
    int u = __shfl_up(inc, d, 64);
    if (lane >= d) inc += u;
  }
  if (lane == 63) wsum[w] = inc;
  __syncthreads();
  if (t == 0) {
    int acc = 0;
#pragma unroll
    for (int i = 0; i < 16; ++i) { woff[i] = acc; acc += wsum[i]; }
    woff[16] = acc;
    rowstart[NN] = acc;
  }
  __syncthreads();
  int excl = woff[w] + inc - s;   // exclusive prefix for this thread's 4 nodes
  int r0 = excl, r1 = r0 + v.x, r2 = r1 + v.y, r3 = r2 + v.z;
  int4 rs; rs.x = r0; rs.y = r1; rs.z = r2; rs.w = r3;
  *(int4*)(rowstart + t * 4) = rs;
  *(int4*)(cursor + t * 4) = rs;
}

__global__ void k_scatter(const void* __restrict__ ei, const int* __restrict__ flag,
                          int* __restrict__ cursor, int* __restrict__ csr) {
  int e = blockIdx.x * blockDim.x + threadIdx.x;
  if (e >= NE) return;
  int is32 = flag[0];
  int s = edge_at(ei, is32, e);
  int d = edge_at(ei, is32, NE + e);
  int pos = atomicAdd(&cursor[d], 1);
  csr[pos] = s;
}

// ---------- mean aggregation: one wave per node, 8-deep MLP ----------
// Previous version exposed ~350ns latency per row-load with ~4 in flight
// (25-45us). Here: preload 8 csr indices (independent), then 8 independent
// 512B row loads in flight, 4 accumulator pairs to break FMA chains.
// 1024 blocks = 16 waves/CU of TLP on top.
__global__ __launch_bounds__(256) void k_aggregate(
    const float* __restrict__ x, const int* __restrict__ rowstart,
    const int* __restrict__ csr, float* __restrict__ agg) {
  int wid = (blockIdx.x * blockDim.x + threadIdx.x) >> 6;
  int lane = threadIdx.x & 63;
  if (wid >= NN) return;
  int s0 = rowstart[wid], s1 = rowstart[wid + 1];
  float a0 = 0.f, a1 = 0.f, b0 = 0.f, b1 = 0.f;
  float c0 = 0.f, c1 = 0.f, d0 = 0.f, d1 = 0.f;
  int e = s0;
  for (; e + 8 <= s1; e += 8) {
    int i0 = csr[e+0], i1 = csr[e+1], i2 = csr[e+2], i3 = csr[e+3];
    int i4 = csr[e+4], i5 = csr[e+5], i6 = csr[e+6], i7 = csr[e+7];
    float2 v0 = *((const float2*)(x + (size_t)i0 * UF) + lane);
    float2 v1 = *((const float2*)(x + (size_t)i1 * UF) + lane);
    float2 v2 = *((const float2*)(x + (size_t)i2 * UF) + lane);
    float2 v3 = *((const float2*)(x + (size_t)i3 * UF) + lane);
    float2 v4 = *((const float2*)(x + (size_t)i4 * UF) + lane);
    float2 v5 = *((const float2*)(x + (size_t)i5 * UF) + lane);
    float2 v6 = *((const float2*)(x + (size_t)i6 * UF) + lane);
    float2 v7 = *((const float2*)(x + (size_t)i7 * UF) + lane);
    a0 += v0.x; a1 += v0.y; b0 += v1.x; b1 += v1.y;
    c0 += v2.x; c1 += v2.y; d0 += v3.x; d1 += v3.y;
    a0 += v4.x; a1 += v4.y; b0 += v5.x; b1 += v5.y;
    c0 += v6.x; c1 += v6.y; d0 += v7.x; d1 += v7.y;
  }
  for (; e < s1; ++e) {
    int s = csr[e];
    float2 v = *((const float2*)(x + (size_t)s * UF) + lane);
    a0 += v.x; a1 += v.y;
  }
  float f0 = (a0 + b0) + (c0 + d0);
  float f1 = (a1 + b1) + (c1 + d1);
  float inv = 1.0f / (float)max(s1 - s0, 1);
  float2 r; r.x = f0 * inv; r.y = f1 * inv;
  *((float2*)(agg + (size_t)wid * UF) + lane) = r;
}

// ---------- SAGE layer as one K=256 GEMM: A'=[agg|in], W'=[Wl|Wr], LDS-staged ----------
template<bool TANH>
__global__ __launch_bounds__(256) void k_layer(
    const float* __restrict__ agg, const float* __restrict__ in,
    const float* __restrict__ Wl, const float* __restrict__ bl,
    const float* __restrict__ Wr, float* __restrict__ out) {
  __shared__ float As[16][260];    // 16 nodes x K=256 (+pad)
  __shared__ float Ws[32][132];    // K-chunk x 128 outs (+pad)
  const int t = threadIdx.x;
  const int base = blockIdx.x * 16;

  // stage A' once: 1024 float4, 4 per thread
#pragma unroll
  for (int r = 0; r < 4; ++r) {
    int idx = t + 256 * r;
    int row = idx >> 6;
    int k = (idx & 63) * 4;
    const float* src = (k < 128) ? (agg + (size_t)(base + row) * UF + k)
                                 : (in  + (size_t)(base + row) * UF + (k - 128));
    *(float4*)&As[row][k] = *(const float4*)src;
  }

  const int o0 = (t & 31) * 4;
  const int n0 = (t >> 5) * 2;
  const int wo = t & 127;          // W-stage: output row handled by this thread
  const int kqb = (t >> 7) * 4;    // W-stage: which 4 of the 8 float4-groups
  float acc[2][4] = {};

  for (int kc = 0; kc < 8; ++kc) {
    __syncthreads();
#pragma unroll
    for (int q = 0; q < 4; ++q) {
      int kq = kqb + q;                       // 0..7
      int kg = kc * 32 + kq * 4;              // global k of this float4
      const float* src = (kg < 128) ? (Wl + (size_t)wo * UF + kg)
                                    : (Wr + (size_t)wo * UF + (kg - 128));
      float4 w = *(const float4*)src;
      Ws[kq * 4 + 0][wo] = w.x;
      Ws[kq * 4 + 1][wo] = w.y;
      Ws[kq * 4 + 2][wo] = w.z;
      Ws[kq * 4 + 3][wo] = w.w;
    }
    __syncthreads();
#pragma unroll 4
    for (int kw = 0; kw < 8; ++kw) {
      int k = kc * 32 + kw * 4;
      float4 a0 = *(const float4*)&As[n0][k];
      float4 a1 = *(const float4*)&As[n0 + 1][k];
      float4 w0 = *(const float4*)&Ws[kw * 4 + 0][o0];
      float4 w1 = *(const float4*)&Ws[kw * 4 + 1][o0];
      float4 w2 = *(const float4*)&Ws[kw * 4 + 2][o0];
      float4 w3 = *(const float4*)&Ws[kw * 4 + 3][o0];
      acc[0][0] = fmaf(a0.x, w0.x, acc[0][0]); acc[0][1] = fmaf(a0.x, w0.y, acc[0][1]);
      acc[0][2] = fmaf(a0.x, w0.z, acc[0][2]); acc[0][3] = fmaf(a0.x, w0.w, acc[0][3]);
      acc[1][0] = fmaf(a1.x, w0.x, acc[1][0]); acc[1][1] = fmaf(a1.x, w0.y, acc[1][1]);
      acc[1][2] = fmaf(a1.x, w0.z, acc[1][2]); acc[1][3] = fmaf(a1.x, w0.w, acc[1][3]);
      acc[0][0] = fmaf(a0.y, w1.x, acc[0][0]); acc[0][1] = fmaf(a0.y, w1.y, acc[0][1]);
      acc[0][2] = fmaf(a0.y, w1.z, acc[0][2]); acc[0][3] = fmaf(a0.y, w1.w, acc[0][3]);
      acc[1][0] = fmaf(a1.y, w1.x, acc[1][0]); acc[1][1] = fmaf(a1.y, w1.y, acc[1][1]);
      acc[1][2] = fmaf(a1.y, w1.z, acc[1][2]); acc[1][3] = fmaf(a1.y, w1.w, acc[1][3]);
      acc[0][0] = fmaf(a0.z, w2.x, acc[0][0]); acc[0][1] = fmaf(a0.z, w2.y, acc[0][1]);
      acc[0][2] = fmaf(a0.z, w2.z, acc[0][2]); acc[0][3] = fmaf(a0.z, w2.w, acc[0][3]);
      acc[1][0] = fmaf(a1.z, w2.x, acc[1][0]); acc[1][1] = fmaf(a1.z, w2.y, acc[1][1]);
      acc[1][2] = fmaf(a1.z, w2.z, acc[1][2]); acc[1][3] = fmaf(a1.z, w2.w, acc[1][3]);
      acc[0][0] = fmaf(a0.w, w3.x, acc[0][0]); acc[0][1] = fmaf(a0.w, w3.y, acc[0][1]);
      acc[0][2] = fmaf(a0.w, w3.z, acc[0][2]); acc[0][3] = fmaf(a0.w, w3.w, acc[0][3]);
      acc[1][0] = fmaf(a1.w, w3.x, acc[1][0]); acc[1][1] = fmaf(a1.w, w3.y, acc[1][1]);
      acc[1][2] = fmaf(a1.w, w3.z, acc[1][2]); acc[1][3] = fmaf(a1.w, w3.w, acc[1][3]);
    }
  }
#pragma unroll
  for (int i = 0; i < 2; ++i) {
    float4 r;
    r.x = acc[i][0] + bl[o0 + 0];
    r.y = acc[i][1] + bl[o0 + 1];
    r.z = acc[i][2] + bl[o0 + 2];
    r.w = acc[i][3] + bl[o0 + 3];
    if (TANH) { r.x = tanhf(r.x); r.y = tanhf(r.y); r.z = tanhf(r.z); r.w = tanhf(r.w); }
    *(float4*)(out + (size_t)(base + n0 + i) * UF + o0) = r;
  }
}

// ---------- fused actor+critic heads (KC=16, two W pairs) ----------
__global__ __launch_bounds__(256) void k_heads(
    const float* __restrict__ agg, const float* __restrict__ in,
    const float* __restrict__ Wa_l, const float* __restrict__ ba_l,
    const float* __restrict__ Wa_r,
    const float* __restrict__ Wcr_l, const float* __restrict__ bcr_l,
    const float* __restrict__ Wcr_r,
    const float* __restrict__ Wfa, const float* __restrict__ Wfc,
    float* __restrict__ a1, float* __restrict__ a2, float* __restrict__ cp) {
  __shared__ float As[16][260];
  __shared__ float WsA[16][132];
  __shared__ float WsC[16][132];
  __shared__ float red[3][16][33];
  const int t = threadIdx.x;
  const int base = blockIdx.x * 16;

#pragma unroll
  for (int r = 0; r < 4; ++r) {
    int idx = t + 256 * r;
    int row = idx >> 6;
    int k = (idx & 63) * 4;
    const float* src = (k < 128) ? (agg + (size_t)(base + row) * UF + k)
                                 : (in  + (size_t)(base + row) * UF + (k - 128));
    *(float4*)&As[row][k] = *(const float4*)src;
  }

  const int og = t & 31;
  const int o0 = og * 4;
  const int n0 = (t >> 5) * 2;
  const int wo = t & 127;
  const int kqb = (t >> 7) * 2;    // which 2 of the 4 float4-groups (KC=16)
  float accA[2][4] = {};
  float accC[2][4] = {};

  for (int kc = 0; kc < 16; ++kc) {
    __syncthreads();
#pragma unroll
    for (int q = 0; q < 2; ++q) {
      int kq = kqb + q;                       // 0..3
      int kg = kc * 16 + kq * 4;
      const float* sA = (kg < 128) ? (Wa_l  + (size_t)wo * UF + kg)
                                   : (Wa_r  + (size_t)wo * UF + (kg - 128));
      const float* sC = (kg < 128) ? (Wcr_l + (size_t)wo * UF + kg)
                                   : (Wcr_r + (size_t)wo * UF + (kg - 128));
      float4 wa = *(const float4*)sA;
      float4 wc = *(const float4*)sC;
      WsA[kq*4+0][wo] = wa.x; WsA[kq*4+1][wo] = wa.y;
      WsA[kq*4+2][wo] = wa.z; WsA[kq*4+3][wo] = wa.w;
      WsC[kq*4+0][wo] = wc.x; WsC[kq*4+1][wo] = wc.y;
      WsC[kq*4+2][wo] = wc.z; WsC[kq*4+3][wo] = wc.w;
    }
    __syncthreads();
#pragma unroll 2
    for (int kw = 0; kw < 4; ++kw) {
      int k = kc * 16 + kw * 4;
      float4 a0 = *(const float4*)&As[n0][k];
      float4 a1v = *(const float4*)&As[n0 + 1][k];
#pragma unroll
      for (int j = 0; j < 4; ++j) {
        float4 wa = *(const float4*)&WsA[kw * 4 + j][o0];
        float4 wc = *(const float4*)&WsC[kw * 4 + j][o0];
        float e0 = (j == 0) ? a0.x : (j == 1) ? a0.y : (j == 2) ? a0.z : a0.w;
        float e1 = (j == 0) ? a1v.x : (j == 1) ? a1v.y : (j == 2) ? a1v.z : a1v.w;
        accA[0][0] = fmaf(e0, wa.x, accA[0][0]); accA[0][1] = fmaf(e0, wa.y, accA[0][1]);
        accA[0][2] = fmaf(e0, wa.z, accA[0][2]); accA[0][3] = fmaf(e0, wa.w, accA[0][3]);
        accA[1][0] = fmaf(e1, wa.x, accA[1][0]); accA[1][1] = fmaf(e1, wa.y, accA[1][1]);
        accA[1][2] = fmaf(e1, wa.z, accA[1][2]); accA[1][3] = fmaf(e1, wa.w, accA[1][3]);
        accC[0][0] = fmaf(e0, wc.x, accC[0][0]); accC[0][1] = fmaf(e0, wc.y, accC[0][1]);
        accC[0][2] = fmaf(e0, wc.z, accC[0][2]); accC[0][3] = fmaf(e0, wc.w, accC[0][3]);
        accC[1][0] = fmaf(e1, wc.x, accC[1][0]); accC[1][1] = fmaf(e1, wc.y, accC[1][1]);
        accC[1][2] = fmaf(e1, wc.z, accC[1][2]); accC[1][3] = fmaf(e1, wc.w, accC[1][3]);
      }
    }
  }
  // biases + project to a1/a2/cp partials
#pragma unroll
  for (int i = 0; i < 2; ++i) {
    float pa1 = 0.f, pa2 = 0.f, pc = 0.f;
#pragma unroll
    for (int j = 0; j < 4; ++j) {
      float xa = accA[i][j] + ba_l[o0 + j];
      float xc = accC[i][j] + bcr_l[o0 + j];
      pa1 = fmaf(xa, Wfa[o0 + j], pa1);
      pa2 = fmaf(xa, Wfa[UF + o0 + j], pa2);
      pc  = fmaf(xc, Wfc[o0 + j], pc);
    }
    red[0][n0 + i][og] = pa1;
    red[1][n0 + i][og] = pa2;
    red[2][n0 + i][og] = pc;
  }
  __syncthreads();
  if (t < 48) {
    int q = t >> 4, n = t & 15;
    float s = 0.f;
#pragma unroll
    for (int j = 0; j < 32; ++j) s += red[q][n][j];
    float* dst = (q == 0) ? a1 : (q == 1) ? a2 : cp;
    dst[base + n] = s;
  }
}

// ---------- global reductions: LSE constant + critic scalar (shfl, 2 barriers) ----------
__global__ __launch_bounds__(1024) void k_reduce(
    const float* __restrict__ a1, const float* __restrict__ a2,
    const float* __restrict__ cp, const float* __restrict__ bfc,
    float* __restrict__ consts, float* __restrict__ outc) {
  __shared__ float r0[16], r1[16], r2[16], r3[16], r4[16];
  const int t = threadIdx.x, lane = t & 63, w = t >> 6;
  float4 X = *(const float4*)(a1 + t * 4);
  float4 Y = *(const float4*)(a2 + t * 4);
  float4 C = *(const float4*)(cp + t * 4);
  float mx = fmaxf(fmaxf(X.x, X.y), fmaxf(X.z, X.w));
  float my = fmaxf(fmaxf(Y.x, Y.y), fmaxf(Y.z, Y.w));
#pragma unroll
  for (int d = 1; d < 64; d <<= 1) {
    mx = fmaxf(mx, __shfl_xor(mx, d, 64));
    my = fmaxf(my, __shfl_xor(my, d, 64));
  }
  if (lane == 0) { r0[w] = mx; r1[w] = my; }
  __syncthreads();
  float m1 = r0[0], m2 = r1[0];
#pragma unroll
  for (int i = 1; i < 16; ++i) { m1 = fmaxf(m1, r0[i]); m2 = fmaxf(m2, r1[i]); }
  float e1 = expf(X.x - m1) + expf(X.y - m1) + expf(X.z - m1) + expf(X.w - m1);
  float e2 = expf(Y.x - m2) + expf(Y.y - m2) + expf(Y.z - m2) + expf(Y.w - m2);
  float sc = C.x + C.y + C.z + C.w;
#pragma unroll
  for (int d = 1; d < 64; d <<= 1) {
    e1 += __shfl_xor(e1, d, 64);
    e2 += __shfl_xor(e2, d, 64);
    sc += __shfl_xor(sc, d, 64);
  }
  if (lane == 0) { r2[w] = e1; r3[w] = e2; r4[w] = sc; }
  __syncthreads();
  if (t == 0) {
    float s1 = 0.f, s2 = 0.f, scs = 0.f;
#pragma unroll
    for (int i = 0; i < 16; ++i) { s1 += r2[i]; s2 += r3[i]; scs += r4[i]; }
    consts[0] = -(m1 + m2 + logf(s1) + logf(s2));
    outc[0] = tanhf(scs * (1.0f / (float)NN) + bfc[0]);
  }
}

// ---------- N^2 output write ----------
__global__ __launch_bounds__(256) void k_write(
    const float* __restrict__ a1, const float* __restrict__ a2,
    const float* __restrict__ consts, float* __restrict__ out) {
  int gid = blockIdx.x * 256 + threadIdx.x;        // one float4 per thread
  int row = gid >> 10;                             // 1024 float4 per row
  int c = (gid & 1023) * 4;
  float C = consts[0] + a1[row];
  float4 v = *(const float4*)(a2 + c);
  float4 r; r.x = v.x + C; r.y = v.y + C; r.z = v.z + C; r.w = v.w + C;
  *(float4*)(out + (size_t)gid * 4) = r;
}

extern "C" void kernel_launch(void* const* d_in, const int* in_sizes, int n_in,
                              void* d_out, int out_size, void* d_ws, size_t ws_size,
                              hipStream_t stream) {
  const float* x     = (const float*)d_in[0];
  const void*  ei    = d_in[1];
  const float* Wf_l  = (const float*)d_in[3];
  const float* bf_l  = (const float*)d_in[4];
  const float* Wf_r  = (const float*)d_in[5];
  const float* Wcm_l = (const float*)d_in[6];
  const float* bcm_l = (const float*)d_in[7];
  const float* Wcm_r = (const float*)d_in[8];
  const float* Wa_l  = (const float*)d_in[9];
  const float* ba_l  = (const float*)d_in[10];
  const float* Wa_r  = (const float*)d_in[11];
  const float* Wcr_l = (const float*)d_in[12];
  const float* bcr_l = (const float*)d_in[13];
  const float* Wcr_r = (const float*)d_in[14];
  const float* Wfa   = (const float*)d_in[15];
  const float* Wfc   = (const float*)d_in[17];
  const float* bfc   = (const float*)d_in[18];
  float* out = (float*)d_out;

  char* b = (char*)d_ws;
  size_t off = 0;
  int* flag = (int*)(b + off); off += 256;
  float* consts = (float*)(b + off); off += 256;
  int* deg = (int*)(b + off); off += (size_t)NN * 4;     // contiguous after flag region? (memset covers flag..deg below)
  int* rowstart = (int*)(b + off); off += (size_t)(NN + 64) * 4;
  int* cursor = (int*)(b + off); off += (size_t)NN * 4;
  int* csr = (int*)(b + off); off += (size_t)NE * 4;
  float* a1 = (float*)(b + off); off += (size_t)NN * 4;
  float* a2 = (float*)(b + off); off += (size_t)NN * 4;
  float* cp = (float*)(b + off); off += (size_t)NN * 4;
  float* agg = (float*)(b + off); off += (size_t)NN * UF * 4;
  float* h1 = (float*)(b + off); off += (size_t)NN * UF * 4;
  float* h2 = (float*)(b + off); off += (size_t)NN * UF * 4;
  if (ws_size < off) return;

  // zero flag (int64 assumed) + consts pad + deg in one memset node
  hipMemsetAsync(d_ws, 0, 512 + (size_t)NN * 4, stream);
  k_detect<<<NE / 256, 256, 0, stream>>>((const long long*)ei, flag);
  k_count<<<NE / 256, 256, 0, stream>>>(ei, flag, deg);
  k_scan<<<1, 1024, 0, stream>>>(deg, rowstart, cursor);
  k_scatter<<<NE / 256, 256, 0, stream>>>(ei, flag, cursor, csr);

  k_aggregate<<<NN / 4, 256, 0, stream>>>(x, rowstart, csr, agg);
  k_layer<true><<<NN / 16, 256, 0, stream>>>(agg, x, Wf_l, bf_l, Wf_r, h1);
  k_aggregate<<<NN / 4, 256, 0, stream>>>(h1, rowstart, csr, agg);
  k_layer<true><<<NN / 16, 256, 0, stream>>>(agg, h1, Wcm_l, bcm_l, Wcm_r, h2);
  k_aggregate<<<NN / 4, 256, 0, stream>>>(h2, rowstart, csr, agg);
  k_heads<<<NN / 16, 256, 0, stream>>>(agg, h2, Wa_l, ba_l, Wa_r,
                                       Wcr_l, bcr_l, Wcr_r, Wfa, Wfc, a1, a2, cp);
  k_reduce<<<1, 1024, 0, stream>>>(a1, a2, cp, bfc, consts, out + (size_t)NN * NN);
  k_write<<<(NN * NN) / 1024, 256, 0, stream>>>(a1, a2, consts, out);
}